// Round 9
// baseline (27693.027 us; speedup 1.0000x reference)
//
#include <hip/hip_runtime.h>
#include <hip/hip_bf16.h>
#include <stdint.h>

#define HID     1024
#define NSTEP   4096
#define NBLK    128
#define CWAVES  8                 // compute waves per block (1 unit each)
#define THREADS ((CWAVES + 1) * 64)   // + 1 dedicated poller wave

typedef unsigned int u32x4 __attribute__((ext_vector_type(4)));
typedef float        f32x4 __attribute__((ext_vector_type(4)));

// ---------------- ws layout ----------------
// [0, 16MiB)               W' = W_hh + W_ih @ W_dec   (4096 x 1024 f32)
// [16MiB, +16KiB)          b' = b_ih+b_hh+W_ih@b_dec  (4096 f32)
// [.. +16KiB)              ginit = W_ih@x + b_ih+b_hh (4096 f32)
// [.. +16KiB)              hbuf: 2 slots x 1024 x u64 {val,tag}
// [16MiB+64KiB, +16MiB)    H history: 4096 x 1024 f32

__device__ __forceinline__ float d4v(f32x4 a, f32x4 b) {
    return fmaf(a.x, b.x, fmaf(a.y, b.y, fmaf(a.z, b.z, a.w * b.w)));
}

// ---- prep: b', ginit, clear tags ----
__global__ void k_prep(const float* __restrict__ x, const float* __restrict__ Wih,
                       const float* __restrict__ bih, const float* __restrict__ bhh,
                       const float* __restrict__ bdec,
                       float* __restrict__ bp, float* __restrict__ gi,
                       unsigned long long* __restrict__ hbuf) {
    int i = blockIdx.x * 256 + threadIdx.x;   // 0 .. 8191
    if (i < 4096) {
        float base = bih[i] + bhh[i];
        float s_b = base, s_g = base;
#pragma unroll
        for (int d = 0; d < 11; ++d) {
            float w = Wih[i * 11 + d];
            s_b = fmaf(w, bdec[d], s_b);
            s_g = fmaf(w, x[d], s_g);
        }
        bp[i] = s_b;
        gi[i] = s_g;
    }
    if (i < 2 * 1024) hbuf[i] = 0ULL;         // clear both parity slots
}

// ---- fold: W' = W_hh + W_ih @ W_dec ----
__global__ void k_fold(const float* __restrict__ Wih, const float* __restrict__ Whh,
                       const float* __restrict__ Wdec, float* __restrict__ Wp) {
    int idx = blockIdx.x * 256 + threadIdx.x;       // 0 .. 4M-1
    int r = idx >> 10, k = idx & 1023;
    float acc = Whh[idx];
#pragma unroll
    for (int d = 0; d < 11; ++d)
        acc = fmaf(Wih[r * 11 + d], Wdec[d * HID + k], acc);
    Wp[idx] = acc;
}

// ---- the sequential LSTM recurrence ----
// 128 blocks x 9 waves: waves 0-7 each own one unit; wave 8 is the block's
// dedicated poller (only agent that touches the fabric for sync).
__global__ __launch_bounds__(THREADS) void lstm_seq(
    const float* __restrict__ Wp, const float* __restrict__ bp,
    const float* __restrict__ gi, unsigned long long* hbuf,
    float* __restrict__ Hh) {
    const int tid  = threadIdx.x;
    const int wv   = tid >> 6;
    const int lane = tid & 63;
    const int unit = blockIdx.x * CWAVES + wv;      // valid for wv < 8

    __shared__ float hs[2][HID];

    // weight bases for this wave's unit (gate q, chunk j at +1024*j bytes)
    const f32x4* wb0 = (const f32x4*)Wp + ((size_t)unit             ) * 256 + lane;
    const f32x4* wb1 = (const f32x4*)Wp + ((size_t)unit + 1024      ) * 256 + lane;
    const f32x4* wb2 = (const f32x4*)Wp + ((size_t)unit + 2048      ) * 256 + lane;
    const f32x4* wb3 = (const f32x4*)Wp + ((size_t)unit + 3072      ) * 256 + lane;

    float bpv[4], giv[4];
    if (wv < CWAVES) {
#pragma unroll
        for (int q = 0; q < 4; ++q) {
            bpv[q] = bp[unit + q * 1024];
            giv[q] = gi[unit + q * 1024];
        }
    }

    float c = 0.f;

#pragma unroll 1
    for (int t = 1; t <= NSTEP; ++t) {
        f32x4 w00, w01, w02, w03, w10, w11, w12, w13;
        f32x4 w20, w21, w22, w23, w30, w31, w32, w33;

        if (wv < CWAVES) {
            // prefetch this step's weights NOW; latency hides under the poll wait
#define LDQ(a, b, cc, d, base)                                              \
            asm volatile("global_load_dwordx4 %0, %4, off\n\t"              \
                         "global_load_dwordx4 %1, %4, off offset:1024\n\t"  \
                         "global_load_dwordx4 %2, %4, off offset:2048\n\t"  \
                         "global_load_dwordx4 %3, %4, off offset:3072"      \
                         : "=&v"(a), "=&v"(b), "=&v"(cc), "=&v"(d)          \
                         : "v"(base))
            LDQ(w00, w01, w02, w03, wb0);
            LDQ(w10, w11, w12, w13, wb1);
            LDQ(w20, w21, w22, w23, wb2);
            LDQ(w30, w31, w32, w33, wb3);
#undef LDQ
        }

        if (t > 1) {
            const int slot = (t - 1) & 1;
            if (wv == CWAVES) {
                // poller: lane owns pairs [lane*16, lane*16+16) = 128B
                const unsigned long long* src = hbuf + slot * HID + lane * 16;
                const unsigned want = (unsigned)(t - 1);
                u32x4 r0, r1, r2, r3, r4, r5, r6, r7;
                for (;;) {
                    asm volatile(
                        "global_load_dwordx4 %0, %8, off sc1\n\t"
                        "global_load_dwordx4 %1, %8, off offset:16 sc1\n\t"
                        "global_load_dwordx4 %2, %8, off offset:32 sc1\n\t"
                        "global_load_dwordx4 %3, %8, off offset:48 sc1\n\t"
                        "global_load_dwordx4 %4, %8, off offset:64 sc1\n\t"
                        "global_load_dwordx4 %5, %8, off offset:80 sc1\n\t"
                        "global_load_dwordx4 %6, %8, off offset:96 sc1\n\t"
                        "global_load_dwordx4 %7, %8, off offset:112 sc1\n\t"
                        "s_waitcnt vmcnt(0)"
                        : "=&v"(r0), "=&v"(r1), "=&v"(r2), "=&v"(r3),
                          "=&v"(r4), "=&v"(r5), "=&v"(r6), "=&v"(r7)
                        : "v"(src) : "memory");
                    unsigned ok = (r0.y == want) & (r0.w == want)
                                & (r1.y == want) & (r1.w == want)
                                & (r2.y == want) & (r2.w == want)
                                & (r3.y == want) & (r3.w == want)
                                & (r4.y == want) & (r4.w == want)
                                & (r5.y == want) & (r5.w == want)
                                & (r6.y == want) & (r6.w == want)
                                & (r7.y == want) & (r7.w == want);
                    if (ok) break;
                }
                float* dst = &hs[slot][lane * 16];
                *(float4*)(dst +  0) = make_float4(__uint_as_float(r0.x), __uint_as_float(r0.z),
                                                   __uint_as_float(r1.x), __uint_as_float(r1.z));
                *(float4*)(dst +  4) = make_float4(__uint_as_float(r2.x), __uint_as_float(r2.z),
                                                   __uint_as_float(r3.x), __uint_as_float(r3.z));
                *(float4*)(dst +  8) = make_float4(__uint_as_float(r4.x), __uint_as_float(r4.z),
                                                   __uint_as_float(r5.x), __uint_as_float(r5.z));
                *(float4*)(dst + 12) = make_float4(__uint_as_float(r6.x), __uint_as_float(r6.z),
                                                   __uint_as_float(r7.x), __uint_as_float(r7.z));
            }
            __syncthreads();
        }

        if (wv < CWAVES) {
            float s[4];
            if (t == 1) {
                asm volatile("s_waitcnt vmcnt(0)" ::: "memory");  // retire prefetch
#pragma unroll
                for (int q = 0; q < 4; ++q) s[q] = giv[q];
            } else {
                const int slot = (t - 1) & 1;
                const f32x4* h4 = (const f32x4*)hs[slot];
                f32x4 h0 = h4[lane], h1 = h4[lane + 64],
                      h2 = h4[lane + 128], h3 = h4[lane + 192];
                asm volatile("s_waitcnt vmcnt(0)" ::: "memory");  // weights ready
                __builtin_amdgcn_sched_barrier(0);
                s[0] = d4v(w00, h0) + d4v(w01, h1) + d4v(w02, h2) + d4v(w03, h3);
                s[1] = d4v(w10, h0) + d4v(w11, h1) + d4v(w12, h2) + d4v(w13, h3);
                s[2] = d4v(w20, h0) + d4v(w21, h1) + d4v(w22, h2) + d4v(w23, h3);
                s[3] = d4v(w30, h0) + d4v(w31, h1) + d4v(w32, h2) + d4v(w33, h3);
#pragma unroll
                for (int m = 32; m >= 1; m >>= 1) {
#pragma unroll
                    for (int q = 0; q < 4; ++q) s[q] += __shfl_xor(s[q], m);
                }
#pragma unroll
                for (int q = 0; q < 4; ++q) s[q] += bpv[q];
            }

            // pointwise LSTM (replicated across lanes; c register-resident)
            float I = 1.f / (1.f + __expf(-s[0]));
            float F = 1.f / (1.f + __expf(-s[1]));
            float G = 1.f - 2.f / (__expf(2.f * s[2]) + 1.f);   // tanh
            float O = 1.f / (1.f + __expf(-s[3]));
            c = fmaf(F, c, I * G);
            float h = O * (1.f - 2.f / (__expf(2.f * c) + 1.f));

            if (lane == 0) {
                Hh[(size_t)(t - 1) * HID + unit] = h;   // history for decoder
                unsigned long long pair =
                    ((unsigned long long)(unsigned)t << 32) |
                    (unsigned long long)__float_as_uint(h);
                __hip_atomic_store(hbuf + (t & 1) * HID + unit, pair,
                                   __ATOMIC_RELAXED, __HIP_MEMORY_SCOPE_AGENT);
            }
        }
    }
}

// ---- decoder over the whole history: out[r][d] = W_dec[d] . H[r] + b_dec[d] ----
__global__ void k_dec(const float* __restrict__ Hh, const float* __restrict__ Wdec,
                      const float* __restrict__ bdec, float* __restrict__ out) {
    int idx = blockIdx.x * 256 + threadIdx.x;
    if (idx >= NSTEP * 11) return;
    int r = idx / 11, d = idx - r * 11;
    const float4* h4 = (const float4*)(Hh + (size_t)r * HID);
    const float4* w4 = (const float4*)(Wdec + (size_t)d * HID);
    float acc = 0.f;
#pragma unroll 4
    for (int k = 0; k < HID / 4; ++k) {
        float4 a = h4[k], b = w4[k];
        acc = fmaf(a.x, b.x, fmaf(a.y, b.y, fmaf(a.z, b.z, fmaf(a.w, b.w, acc))));
    }
    out[idx] = acc + bdec[d];
}

extern "C" void kernel_launch(void* const* d_in, const int* in_sizes, int n_in,
                              void* d_out, int out_size, void* d_ws, size_t ws_size,
                              hipStream_t stream) {
    const float* x    = (const float*)d_in[0];
    const float* Wih  = (const float*)d_in[1];
    const float* Whh  = (const float*)d_in[2];
    const float* bih  = (const float*)d_in[3];
    const float* bhh  = (const float*)d_in[4];
    const float* Wdec = (const float*)d_in[5];
    const float* bdec = (const float*)d_in[6];
    float* out = (float*)d_out;

    char* ws = (char*)d_ws;
    float* Wp = (float*)ws;                                      // 16 MiB
    float* bp = (float*)(ws + (16u << 20));                      // 16 KiB
    float* gi = bp + 4096;                                       // 16 KiB
    unsigned long long* hbuf = (unsigned long long*)(gi + 4096); // 16 KiB
    float* Hh = (float*)(ws + (16u << 20) + (64u << 10));        // 16 MiB

    k_prep<<<32, 256, 0, stream>>>(x, Wih, bih, bhh, bdec, bp, gi, hbuf);
    k_fold<<<(4096 * 1024) / 256, 256, 0, stream>>>(Wih, Whh, Wdec, Wp);
    lstm_seq<<<NBLK, THREADS, 0, stream>>>(Wp, bp, gi, hbuf, Hh);
    k_dec<<<(NSTEP * 11 + 255) / 256, 256, 0, stream>>>(Hh, Wdec, bdec, out);
}